// Round 8
// baseline (200.413 us; speedup 1.0000x reference)
//
#include <hip/hip_runtime.h>

#define NPT   120000            // points per batch
#define NB    2                 // batches
#define NSEG  262144            // 512*512 pillars
#define NXg   512
#define NSEGT (NB * NSEG)       // 524288 total segments
#define NPTS  (NB * NPT)        // 240000 total points

typedef __attribute__((ext_vector_type(8))) short  bf16x8;
typedef __attribute__((ext_vector_type(4))) float  f32x4;

__device__ __forceinline__ unsigned short f2bf(float f) {
    unsigned u = __float_as_uint(f);
    return (unsigned short)((u + 0x7FFFu + ((u >> 16) & 1u)) >> 16);   // RNE
}

// ---------------------------------------------------------------------------
// K0: zero cnt + tick (custom fill — rocclr fill ran at 18 GB/s for 2 MB)
//     + BN-fold layer-1 weights (transposed bf16) in the extra block.
// ---------------------------------------------------------------------------
__global__ __launch_bounds__(256) void k_init(unsigned int* __restrict__ cnt,
                                              const float* __restrict__ w1,
                                              const float* __restrict__ g1,
                                              const float* __restrict__ b1,
                                              const float* __restrict__ m1,
                                              const float* __restrict__ v1,
                                              unsigned short* __restrict__ wtbf,
                                              float* __restrict__ bias1f,
                                              unsigned int* __restrict__ tick) {
    int t = threadIdx.x;
    if (blockIdx.x < 512) {
        int idx = blockIdx.x * 256 + t;          // 131072 uint4 = 2 MB
        ((uint4*)cnt)[idx] = make_uint4(0u, 0u, 0u, 0u);
        return;
    }
    // prep block
    #pragma unroll
    for (int i = 0; i < 16; ++i) {
        int idx = t + i * 256;                   // idx = c*64 + k
        int c = idx >> 6, k = idx & 63;
        float al = g1[c] * rsqrtf(v1[c] + 1e-3f);
        wtbf[idx] = f2bf(w1[k * 64 + c] * al);
    }
    if (t < 64) bias1f[t] = b1[t] - m1[t] * (g1[t] * rsqrtf(v1[t] + 1e-3f));
    if (t == 0) *tick = 0u;
}

// ---------------------------------------------------------------------------
// K1: pillar id -> count atomic + arrival rank
// ---------------------------------------------------------------------------
__global__ __launch_bounds__(256) void k_stats(const float* __restrict__ pts,
                                               unsigned int* __restrict__ cnt,
                                               unsigned int* __restrict__ rank) {
    int tid = blockIdx.x * 256 + threadIdx.x;
    if (tid >= NPTS) return;
    const float* p = pts + (size_t)tid * 3;
    float x = p[0], y = p[1];
    // EXACT reference arithmetic: floor((x - lo)/vs), IEEE fp32 divide
    int xi = (int)floorf((x - (-51.2f)) / 0.2f);
    int yi = (int)floorf((y - (-51.2f)) / 0.2f);
    xi = min(max(xi, 0), 511);
    yi = min(max(yi, 0), 511);
    int b = (tid >= NPT) ? 1 : 0;
    int gvid = b * NSEG + (yi * NXg + xi);
    rank[tid] = atomicAdd(&cnt[gvid], 1u);
}

// ---------------------------------------------------------------------------
// Scan: block-local exclusive offs + bsum; LAST finishing block scans bsum
// in place (device fence + tick atomic; agent-scope loads).
// Consumers add bsum[g>>10].
// ---------------------------------------------------------------------------
__global__ __launch_bounds__(256) void k_scan1(const unsigned int* __restrict__ cnt,
                                               unsigned int* __restrict__ offs,
                                               unsigned int* __restrict__ bsum,
                                               unsigned int* __restrict__ tick) {
    __shared__ unsigned int s[256];
    __shared__ int lastFlag;
    int t = threadIdx.x;
    size_t base = (size_t)blockIdx.x * 1024 + t * 4;
    uint4 c4 = *(const uint4*)(cnt + base);
    unsigned int tsum = c4.x + c4.y + c4.z + c4.w;
    s[t] = tsum;
    __syncthreads();
    for (int o = 1; o < 256; o <<= 1) {
        unsigned int v = (t >= o) ? s[t - o] : 0u;
        __syncthreads();
        s[t] += v;
        __syncthreads();
    }
    unsigned int pre = s[t] - tsum;          // exclusive within block
    if (t == 255) bsum[blockIdx.x] = s[255];
    uint4 o4;
    o4.x = pre; o4.y = pre + c4.x; o4.z = o4.y + c4.y; o4.w = o4.z + c4.z;
    *(uint4*)(offs + base) = o4;

    // last-block inline scan of bsum[512]
    __threadfence();
    if (t == 0) lastFlag = (atomicAdd(tick, 1u) == 511u);
    __syncthreads();
    if (!lastFlag) return;
    unsigned a = __hip_atomic_load(&bsum[2 * t],     __ATOMIC_RELAXED, __HIP_MEMORY_SCOPE_AGENT);
    unsigned b = __hip_atomic_load(&bsum[2 * t + 1], __ATOMIC_RELAXED, __HIP_MEMORY_SCOPE_AGENT);
    unsigned ts2 = a + b;
    s[t] = ts2;
    __syncthreads();
    for (int o = 1; o < 256; o <<= 1) {
        unsigned int v = (t >= o) ? s[t - o] : 0u;
        __syncthreads();
        s[t] += v;
        __syncthreads();
    }
    unsigned pre2 = s[t] - ts2;
    bsum[2 * t] = pre2;
    bsum[2 * t + 1] = pre2 + a;
}

// ---------------------------------------------------------------------------
// K2: counting-sort apply. pos = offs[gvid] + bsum[g>>10] + rank.
//     comb packs (vid&63)<<18 | tid  (tid < 2^18).
// ---------------------------------------------------------------------------
__global__ __launch_bounds__(256) void k_reorder(const float* __restrict__ pts,
                                                 const unsigned int* __restrict__ rank,
                                                 const unsigned int* __restrict__ offs,
                                                 const unsigned int* __restrict__ bsum,
                                                 float4* __restrict__ sxyz,
                                                 unsigned int* __restrict__ comb) {
    int tid = blockIdx.x * 256 + threadIdx.x;
    if (tid >= NPTS) return;
    const float* p = pts + (size_t)tid * 3;
    float x = p[0], y = p[1], z = p[2];
    int xi = (int)floorf((x - (-51.2f)) / 0.2f);
    int yi = (int)floorf((y - (-51.2f)) / 0.2f);
    xi = min(max(xi, 0), 511);
    yi = min(max(yi, 0), 511);
    int b = (tid >= NPT) ? 1 : 0;
    int gvid = b * NSEG + (yi * NXg + xi);
    unsigned pos = offs[gvid] + bsum[gvid >> 10] + rank[tid];
    sxyz[pos] = make_float4(x, y, z, __int_as_float(gvid));
    comb[pos] = ((unsigned)(gvid & 63) << 18) | (unsigned)tid;
}

// ---------------------------------------------------------------------------
// K3 (fully fused): 64 pillars / 256-thread block (4 waves).
//   stage: layer0 computed in-place from sxyz (4 thr/point x 8 ch):
//          pillar mean + per-sibling h0 recompute -> own + pooled,
//          packed bf16 X-row [own|pool] into XOR-swizzled LDS tile.
//   MFMA : 16 points x 64 ch per wave via 8x mfma_f32_16x16x32_bf16
//   tail : transposed coalesced canvas write
// ---------------------------------------------------------------------------
__global__ __launch_bounds__(256) void k_pfn1(const float4* __restrict__ sxyz,
                                              const unsigned int* __restrict__ comb,
                                              const unsigned int* __restrict__ offs,
                                              const unsigned int* __restrict__ bsum,
                                              const unsigned int* __restrict__ cnt,
                                              const float* __restrict__ w0,
                                              const float* __restrict__ g0,
                                              const float* __restrict__ b0,
                                              const float* __restrict__ m0,
                                              const float* __restrict__ v0,
                                              const unsigned short* __restrict__ wtbf,
                                              const float* __restrict__ bias1f,
                                              float* __restrict__ ptfeat,
                                              float* __restrict__ canvas) {
    __shared__ float w0f[256];               // BN-folded [8][32]
    __shared__ float bias0[32];
    __shared__ unsigned short xlds[64 * 64]; // swizzled bf16 X rows (8KB)
    __shared__ unsigned voxl[64][65];        // fp32 bits, padded
    __shared__ unsigned combs[64];
    __shared__ unsigned offl[64];            // per-pillar start pos
    __shared__ unsigned cntl[64];            // per-pillar count

    int t = threadIdx.x;
    int l = t & 63;                          // lane in wave
    int w = t >> 6;                          // wave 0..3

    int batch = blockIdx.x >> 12;            // 4096 blocks per batch
    int vid0 = (blockIdx.x & 4095) << 6;
    int gvid0 = batch * NSEG + vid0;

    {
        int c = t & 31;
        float al = g0[c] * rsqrtf(v0[c] + 1e-3f);
        w0f[t] = w0[t] * al;
        if (t < 32) bias0[t] = b0[t] - m0[t] * al;
    }
    #pragma unroll
    for (int i = 0; i < 17; ++i) {
        int idx = t + i * 256;
        if (idx < 64 * 65) ((unsigned*)voxl)[idx] = 0u;
    }
    if (t < 64) {
        int g = gvid0 + t;
        offl[t] = offs[g] + bsum[g >> 10];
        cntl[t] = cnt[g];
    }

    unsigned poslo = offs[gvid0] + bsum[gvid0 >> 10];
    unsigned poshi;
    {
        int g2 = gvid0 + 63;
        poshi = offs[g2] + bsum[g2 >> 10] + cnt[g2];
    }

    // B-fragments: lane holds WT[c = n*16 + l%16][k = ks*32 + (l/16)*8 + e]
    bf16x8 bfr[4][2];
    float bia[4];
    #pragma unroll
    for (int n = 0; n < 4; ++n) {
        #pragma unroll
        for (int ks = 0; ks < 2; ++ks)
            bfr[n][ks] = *(const bf16x8*)(wtbf + ((n * 16 + (l & 15)) * 64 +
                                                  ks * 32 + (l >> 4) * 8));
        bia[n] = bias1f[n * 16 + (l & 15)];
    }
    __syncthreads();                         // w0f/voxl/offl ready

    for (unsigned pc = poslo; pc < poshi; pc += 64) {
        unsigned m = min(64u, poshi - pc);

        // ---- stage: fused layer0, 4 threads per point, 8 channels each ----
        {
            int pt = t >> 2, j = t & 3;
            unsigned sw = (unsigned)(pt & 7) << 4;
            unsigned swz_own  = (unsigned)(pt * 128 + j * 16) ^ sw;
            unsigned swz_pool = (unsigned)(pt * 128 + 64 + j * 16) ^ sw;
            uint4 ow = make_uint4(0u, 0u, 0u, 0u);
            uint4 pw = make_uint4(0u, 0u, 0u, 0u);
            if (pt < (int)m) {
                unsigned pos = pc + pt;
                float4 me = sxyz[pos];
                int gvid = __float_as_int(me.w);
                int vloc = gvid & 63;
                int vid = gvid & (NSEG - 1);
                int xi = vid & (NXg - 1), yi = vid >> 9;
                unsigned off = offl[vloc];
                unsigned n = cntl[vloc];
                float sx = 0.f, sy = 0.f, sz = 0.f;
                for (unsigned i = 0; i < n; ++i) {
                    float4 q = sxyz[off + i];
                    sx += q.x; sy += q.y; sz += q.z;
                }
                float inv = 1.0f / (float)n;
                float mx = sx * inv, my = sy * inv, mz = sz * inv;
                float cx = ((float)xi + 0.5f) * 0.2f + (-51.2f);
                float cy = ((float)yi + 0.5f) * 0.2f + (-51.2f);
                float own[8], pool[8];
                #pragma unroll
                for (int c2 = 0; c2 < 8; ++c2) { own[c2] = 0.f; pool[c2] = 0.f; }
                for (unsigned i = 0; i < n; ++i) {
                    float4 q = sxyz[off + i];
                    float f[8] = {q.x, q.y, q.z, q.x - mx, q.y - my, q.z - mz,
                                  q.x - cx, q.y - cy};
                    bool self = (off + i == pos);
                    #pragma unroll
                    for (int c2 = 0; c2 < 8; ++c2) {
                        int c = j * 8 + c2;
                        float acc = bias0[c];
                        #pragma unroll
                        for (int k = 0; k < 8; ++k) acc += f[k] * w0f[k * 32 + c];
                        acc = fmaxf(acc, 0.0f);
                        pool[c2] = fmaxf(pool[c2], acc);
                        if (self) own[c2] = acc;
                    }
                }
                ow.x = (unsigned)f2bf(own[0]) | ((unsigned)f2bf(own[1]) << 16);
                ow.y = (unsigned)f2bf(own[2]) | ((unsigned)f2bf(own[3]) << 16);
                ow.z = (unsigned)f2bf(own[4]) | ((unsigned)f2bf(own[5]) << 16);
                ow.w = (unsigned)f2bf(own[6]) | ((unsigned)f2bf(own[7]) << 16);
                pw.x = (unsigned)f2bf(pool[0]) | ((unsigned)f2bf(pool[1]) << 16);
                pw.y = (unsigned)f2bf(pool[2]) | ((unsigned)f2bf(pool[3]) << 16);
                pw.z = (unsigned)f2bf(pool[4]) | ((unsigned)f2bf(pool[5]) << 16);
                pw.w = (unsigned)f2bf(pool[6]) | ((unsigned)f2bf(pool[7]) << 16);
                if (j == 0) combs[pt] = comb[pos];
            }
            *(uint4*)((char*)xlds + swz_own) = ow;
            *(uint4*)((char*)xlds + swz_pool) = pw;
        }
        __syncthreads();

        // ---- MFMA: 16 points x 64 channels per wave ----
        {
            int row = w * 16 + (l & 15);
            unsigned base = (unsigned)(row * 128 + ((l >> 4) << 4));
            unsigned sw = (unsigned)(row & 7) << 4;
            bf16x8 a0 = *(const bf16x8*)((char*)xlds + ((base + 0) ^ sw));
            bf16x8 a1 = *(const bf16x8*)((char*)xlds + ((base + 64) ^ sw));
            #pragma unroll
            for (int n = 0; n < 4; ++n) {
                f32x4 acc = {0.f, 0.f, 0.f, 0.f};
                acc = __builtin_amdgcn_mfma_f32_16x16x32_bf16(a0, bfr[n][0], acc, 0, 0, 0);
                acc = __builtin_amdgcn_mfma_f32_16x16x32_bf16(a1, bfr[n][1], acc, 0, 0, 0);
                int ch = n * 16 + (l & 15);
                #pragma unroll
                for (int r = 0; r < 4; ++r) {
                    int pidx = w * 16 + (l >> 4) * 4 + r;   // C: row=(l>>4)*4+r
                    if (pidx < (int)m) {
                        unsigned u = combs[pidx];
                        float v = fmaxf(acc[r] + bia[n], 0.0f);
                        ptfeat[(size_t)(u & 0x3FFFFu) * 64 + ch] = v;
                        atomicMax(&voxl[u >> 18][ch], __float_as_uint(v));
                    }
                }
            }
        }
        __syncthreads();
    }

    // ---- transposed canvas write ----
    {
        float* cv = canvas + (size_t)batch * 64 * NSEG + vid0;
        #pragma unroll
        for (int i = 0; i < 16; ++i) {
            int c = i * 4 + w;
            cv[(size_t)c * NSEG + l] = __uint_as_float(voxl[l][c]);
        }
    }
}

// ---------------------------------------------------------------------------
extern "C" void kernel_launch(void* const* d_in, const int* in_sizes, int n_in,
                              void* d_out, int out_size, void* d_ws, size_t ws_size,
                              hipStream_t stream) {
    const float* pts = (const float*)d_in[0];
    const float* w0  = (const float*)d_in[1];
    const float* g0  = (const float*)d_in[2];
    const float* b0  = (const float*)d_in[3];
    const float* m0  = (const float*)d_in[4];
    const float* v0  = (const float*)d_in[5];
    const float* w1  = (const float*)d_in[6];
    const float* g1  = (const float*)d_in[7];
    const float* b1  = (const float*)d_in[8];
    const float* m1  = (const float*)d_in[9];
    const float* v1  = (const float*)d_in[10];
    float* out = (float*)d_out;
    float* ptfeat = out + (size_t)NB * 64 * NSEG;   // point_feats after canvases

    // workspace layout (~11 MB)
    char* ws = (char*)d_ws;
    size_t off = 0;
    unsigned int* cnt   = (unsigned int*)(ws + off); off += (size_t)NSEGT * 4;
    unsigned int* offs  = (unsigned int*)(ws + off); off += (size_t)NSEGT * 4;
    unsigned int* rank  = (unsigned int*)(ws + off); off += (size_t)NPTS * 4;
    unsigned int* comb  = (unsigned int*)(ws + off); off += (size_t)NPTS * 4;
    float4* sxyz        = (float4*)(ws + off);       off += (size_t)NPTS * 16;
    unsigned short* wtbf= (unsigned short*)(ws + off); off += 4096 * 2;
    float* bias1f       = (float*)(ws + off);        off += 64 * 4;
    unsigned int* bsum  = (unsigned int*)(ws + off); off += 512 * 4;
    unsigned int* tick  = (unsigned int*)(ws + off); off += 4;

    int nblk = (NPTS + 255) / 256;
    k_init<<<513, 256, 0, stream>>>(cnt, w1, g1, b1, m1, v1, wtbf, bias1f, tick);
    k_stats<<<nblk, 256, 0, stream>>>(pts, cnt, rank);
    k_scan1<<<NSEGT / 1024, 256, 0, stream>>>(cnt, offs, bsum, tick);
    k_reorder<<<nblk, 256, 0, stream>>>(pts, rank, offs, bsum, sxyz, comb);
    k_pfn1<<<NB * 4096, 256, 0, stream>>>(sxyz, comb, offs, bsum, cnt,
                                          w0, g0, b0, m0, v0,
                                          wtbf, bias1f, ptfeat, out);
}

// Round 9
// 181.001 us; speedup vs baseline: 1.1072x; 1.1072x over previous
//
#include <hip/hip_runtime.h>

#define NPT   120000            // points per batch
#define NB    2                 // batches
#define NSEG  262144            // 512*512 pillars
#define NXg   512
#define NSEGT (NB * NSEG)       // 524288 total segments
#define NPTS  (NB * NPT)        // 240000 total points

typedef __attribute__((ext_vector_type(8))) short  bf16x8;
typedef __attribute__((ext_vector_type(4))) float  f32x4;

__device__ __forceinline__ unsigned short f2bf(float f) {
    unsigned u = __float_as_uint(f);
    return (unsigned short)((u + 0x7FFFu + ((u >> 16) & 1u)) >> 16);   // RNE
}

// ---------------------------------------------------------------------------
// K0: zero cnt + tick (custom fill — rocclr fill ran at 18 GB/s for 2 MB)
//     + BN-fold layer-1 weights (transposed bf16) in the extra block.
// ---------------------------------------------------------------------------
__global__ __launch_bounds__(256) void k_init(unsigned int* __restrict__ cnt,
                                              const float* __restrict__ w1,
                                              const float* __restrict__ g1,
                                              const float* __restrict__ b1,
                                              const float* __restrict__ m1,
                                              const float* __restrict__ v1,
                                              unsigned short* __restrict__ wtbf,
                                              float* __restrict__ bias1f,
                                              unsigned int* __restrict__ tick) {
    int t = threadIdx.x;
    if (blockIdx.x < 512) {
        int idx = blockIdx.x * 256 + t;          // 131072 uint4 = 2 MB
        ((uint4*)cnt)[idx] = make_uint4(0u, 0u, 0u, 0u);
        return;
    }
    // prep block
    #pragma unroll
    for (int i = 0; i < 16; ++i) {
        int idx = t + i * 256;                   // idx = c*64 + k
        int c = idx >> 6, k = idx & 63;
        float al = g1[c] * rsqrtf(v1[c] + 1e-3f);
        wtbf[idx] = f2bf(w1[k * 64 + c] * al);
    }
    if (t < 64) bias1f[t] = b1[t] - m1[t] * (g1[t] * rsqrtf(v1[t] + 1e-3f));
    if (t == 0) *tick = 0u;
}

// ---------------------------------------------------------------------------
// K1: pillar id -> count atomic + arrival rank
// ---------------------------------------------------------------------------
__global__ __launch_bounds__(256) void k_stats(const float* __restrict__ pts,
                                               unsigned int* __restrict__ cnt,
                                               unsigned int* __restrict__ rank) {
    int tid = blockIdx.x * 256 + threadIdx.x;
    if (tid >= NPTS) return;
    const float* p = pts + (size_t)tid * 3;
    float x = p[0], y = p[1];
    // EXACT reference arithmetic: floor((x - lo)/vs), IEEE fp32 divide
    int xi = (int)floorf((x - (-51.2f)) / 0.2f);
    int yi = (int)floorf((y - (-51.2f)) / 0.2f);
    xi = min(max(xi, 0), 511);
    yi = min(max(yi, 0), 511);
    int b = (tid >= NPT) ? 1 : 0;
    int gvid = b * NSEG + (yi * NXg + xi);
    rank[tid] = atomicAdd(&cnt[gvid], 1u);
}

// ---------------------------------------------------------------------------
// Scan: block-local exclusive offs + bsum; LAST finishing block scans bsum
// in place (device fence + tick atomic; agent-scope loads).
// Consumers add bsum[g>>10].
// ---------------------------------------------------------------------------
__global__ __launch_bounds__(256) void k_scan1(const unsigned int* __restrict__ cnt,
                                               unsigned int* __restrict__ offs,
                                               unsigned int* __restrict__ bsum,
                                               unsigned int* __restrict__ tick) {
    __shared__ unsigned int s[256];
    __shared__ int lastFlag;
    int t = threadIdx.x;
    size_t base = (size_t)blockIdx.x * 1024 + t * 4;
    uint4 c4 = *(const uint4*)(cnt + base);
    unsigned int tsum = c4.x + c4.y + c4.z + c4.w;
    s[t] = tsum;
    __syncthreads();
    for (int o = 1; o < 256; o <<= 1) {
        unsigned int v = (t >= o) ? s[t - o] : 0u;
        __syncthreads();
        s[t] += v;
        __syncthreads();
    }
    unsigned int pre = s[t] - tsum;          // exclusive within block
    if (t == 255) bsum[blockIdx.x] = s[255];
    uint4 o4;
    o4.x = pre; o4.y = pre + c4.x; o4.z = o4.y + c4.y; o4.w = o4.z + c4.z;
    *(uint4*)(offs + base) = o4;

    // last-block inline scan of bsum[512]
    __threadfence();
    if (t == 0) lastFlag = (atomicAdd(tick, 1u) == 511u);
    __syncthreads();
    if (!lastFlag) return;
    unsigned a = __hip_atomic_load(&bsum[2 * t],     __ATOMIC_RELAXED, __HIP_MEMORY_SCOPE_AGENT);
    unsigned b = __hip_atomic_load(&bsum[2 * t + 1], __ATOMIC_RELAXED, __HIP_MEMORY_SCOPE_AGENT);
    unsigned ts2 = a + b;
    s[t] = ts2;
    __syncthreads();
    for (int o = 1; o < 256; o <<= 1) {
        unsigned int v = (t >= o) ? s[t - o] : 0u;
        __syncthreads();
        s[t] += v;
        __syncthreads();
    }
    unsigned pre2 = s[t] - ts2;
    bsum[2 * t] = pre2;
    bsum[2 * t + 1] = pre2 + a;
}

// ---------------------------------------------------------------------------
// K2: counting-sort apply. pos = offs[gvid] + bsum[g>>10] + rank.
//     comb packs (vid&63)<<18 | tid  (tid < 2^18).
// ---------------------------------------------------------------------------
__global__ __launch_bounds__(256) void k_reorder(const float* __restrict__ pts,
                                                 const unsigned int* __restrict__ rank,
                                                 const unsigned int* __restrict__ offs,
                                                 const unsigned int* __restrict__ bsum,
                                                 float4* __restrict__ sxyz,
                                                 unsigned int* __restrict__ comb) {
    int tid = blockIdx.x * 256 + threadIdx.x;
    if (tid >= NPTS) return;
    const float* p = pts + (size_t)tid * 3;
    float x = p[0], y = p[1], z = p[2];
    int xi = (int)floorf((x - (-51.2f)) / 0.2f);
    int yi = (int)floorf((y - (-51.2f)) / 0.2f);
    xi = min(max(xi, 0), 511);
    yi = min(max(yi, 0), 511);
    int b = (tid >= NPT) ? 1 : 0;
    int gvid = b * NSEG + (yi * NXg + xi);
    unsigned pos = offs[gvid] + bsum[gvid >> 10] + rank[tid];
    sxyz[pos] = make_float4(x, y, z, __int_as_float(gvid));
    comb[pos] = ((unsigned)(gvid & 63) << 18) | (unsigned)tid;
}

// ---------------------------------------------------------------------------
// K3: PFN layer0, position-parallel. Computes pillar mean AND pillar pooled
//     max by recomputing sibling h0 (siblings contiguous, avg 1.46/point).
//     Writes the complete 128B bf16 X-row [h0 | pooled]  (8 uint4).
// ---------------------------------------------------------------------------
__global__ __launch_bounds__(256) void k_pfn0(const float4* __restrict__ sxyz,
                                              const unsigned int* __restrict__ offs,
                                              const unsigned int* __restrict__ bsum,
                                              const unsigned int* __restrict__ cnt,
                                              const float* __restrict__ w0,
                                              const float* __restrict__ g0,
                                              const float* __restrict__ b0,
                                              const float* __restrict__ m0,
                                              const float* __restrict__ v0,
                                              unsigned short* __restrict__ xbf) {
    __shared__ float w0f[256];   // BN-folded [8][32]
    __shared__ float bias0[32];
    int t = threadIdx.x;
    {
        int c = t & 31;
        float al = g0[c] * rsqrtf(v0[c] + 1e-3f);
        w0f[t] = w0[t] * al;
        if (t < 32) bias0[t] = b0[t] - m0[t] * al;
    }
    __syncthreads();

    int pos = blockIdx.x * 256 + t;
    if (pos >= NPTS) return;

    float4 me = sxyz[pos];
    int gvid = __float_as_int(me.w);
    int vid = gvid & (NSEG - 1);
    int xi = vid & (NXg - 1), yi = vid >> 9;

    unsigned off = offs[gvid] + bsum[gvid >> 10];
    unsigned n   = cnt[gvid];               // >= 1
    float sx = 0.f, sy = 0.f, sz = 0.f;
    for (unsigned i = 0; i < n; ++i) {
        float4 q = sxyz[off + i];
        sx += q.x; sy += q.y; sz += q.z;
    }
    float inv = 1.0f / (float)n;
    float mx = sx * inv, my = sy * inv, mz = sz * inv;
    float cx = ((float)xi + 0.5f) * 0.2f + (-51.2f);
    float cy = ((float)yi + 0.5f) * 0.2f + (-51.2f);

    float own[32], pool[32];
    #pragma unroll
    for (int c = 0; c < 32; ++c) { pool[c] = 0.0f; own[c] = 0.0f; }
    for (unsigned i = 0; i < n; ++i) {
        float4 q = sxyz[off + i];
        float f[8] = {q.x, q.y, q.z, q.x - mx, q.y - my, q.z - mz,
                      q.x - cx, q.y - cy};
        bool self = (off + i == (unsigned)pos);
        #pragma unroll
        for (int c = 0; c < 32; ++c) {
            float acc = bias0[c];
            #pragma unroll
            for (int k = 0; k < 8; ++k) acc += f[k] * w0f[k * 32 + c];
            acc = fmaxf(acc, 0.0f);
            pool[c] = fmaxf(pool[c], acc);
            if (self) own[c] = acc;
        }
    }

    // full 128B row: own -> dst[0..3], pool -> dst[4..7]
    unsigned wv[16];
    uint4* dst = (uint4*)(xbf + (size_t)pos * 64);
    #pragma unroll
    for (int c2 = 0; c2 < 16; ++c2)
        wv[c2] = (unsigned)f2bf(own[2 * c2]) | ((unsigned)f2bf(own[2 * c2 + 1]) << 16);
    dst[0] = make_uint4(wv[0],  wv[1],  wv[2],  wv[3]);
    dst[1] = make_uint4(wv[4],  wv[5],  wv[6],  wv[7]);
    dst[2] = make_uint4(wv[8],  wv[9],  wv[10], wv[11]);
    dst[3] = make_uint4(wv[12], wv[13], wv[14], wv[15]);
    #pragma unroll
    for (int c2 = 0; c2 < 16; ++c2)
        wv[c2] = (unsigned)f2bf(pool[2 * c2]) | ((unsigned)f2bf(pool[2 * c2 + 1]) << 16);
    dst[4] = make_uint4(wv[0],  wv[1],  wv[2],  wv[3]);
    dst[5] = make_uint4(wv[4],  wv[5],  wv[6],  wv[7]);
    dst[6] = make_uint4(wv[8],  wv[9],  wv[10], wv[11]);
    dst[7] = make_uint4(wv[12], wv[13], wv[14], wv[15]);
}

// ---------------------------------------------------------------------------
// K4 (fused MFMA): 64 pillars / 256-thread block (4 waves).
//   stage: linear coalesced copy of X rows (XOR-swizzled LDS), trimmed to
//          ceil16(m) rows; waves whose 16-row slice is empty skip MFMA.
//   B    : 16 points x 64 ch per wave via 8x mfma_f32_16x16x32_bf16
//   C    : transposed coalesced canvas write
// ---------------------------------------------------------------------------
__global__ __launch_bounds__(256) void k_pfn1(const unsigned short* __restrict__ xbf,
                                              const unsigned int* __restrict__ comb,
                                              const unsigned int* __restrict__ offs,
                                              const unsigned int* __restrict__ bsum,
                                              const unsigned int* __restrict__ cnt,
                                              const unsigned short* __restrict__ wtbf,
                                              const float* __restrict__ bias1f,
                                              float* __restrict__ ptfeat,
                                              float* __restrict__ canvas) {
    __shared__ unsigned short xlds[64 * 64]; // swizzled bf16 X rows (8KB)
    __shared__ unsigned voxl[64][65];        // fp32 bits, padded
    __shared__ unsigned combs[64];

    int t = threadIdx.x;
    int l = t & 63;                          // lane in wave
    int w = t >> 6;                          // wave 0..3

    int batch = blockIdx.x >> 12;            // 4096 blocks per batch
    int vid0 = (blockIdx.x & 4095) << 6;
    int gvid0 = batch * NSEG + vid0;

    #pragma unroll
    for (int i = 0; i < 17; ++i) {
        int idx = t + i * 256;
        if (idx < 64 * 65) ((unsigned*)voxl)[idx] = 0u;
    }

    unsigned poslo = offs[gvid0] + bsum[gvid0 >> 10];
    unsigned poshi;
    {
        int g2 = gvid0 + 63;
        poshi = offs[g2] + bsum[g2 >> 10] + cnt[g2];
    }

    // B-fragments: lane holds WT[c = n*16 + l%16][k = ks*32 + (l/16)*8 + e]
    bf16x8 bfr[4][2];
    float bia[4];
    #pragma unroll
    for (int n = 0; n < 4; ++n) {
        #pragma unroll
        for (int ks = 0; ks < 2; ++ks)
            bfr[n][ks] = *(const bf16x8*)(wtbf + ((n * 16 + (l & 15)) * 64 +
                                                  ks * 32 + (l >> 4) * 8));
        bia[n] = bias1f[n * 16 + (l & 15)];
    }
    __syncthreads();                         // voxl init visible (empty-tile path)

    for (unsigned pc = poslo; pc < poshi; pc += 64) {
        unsigned m = min(64u, poshi - pc);
        unsigned mc = (m + 15u) & ~15u;      // rows actually staged/consumed

        // stage: linear coalesced read of 128B rows, swizzled LDS write
        for (int idx = t; idx < (int)(mc * 8); idx += 256) {
            int pt = idx >> 3, seg = idx & 7;
            unsigned lin = (unsigned)(pt * 128 + seg * 16);
            unsigned swz = lin ^ ((unsigned)(pt & 7) << 4);
            bf16x8 val;
            #pragma unroll
            for (int e = 0; e < 8; ++e) val[e] = 0;
            if (pt < (int)m)
                val = *(const bf16x8*)(xbf + (size_t)(pc + pt) * 64 + seg * 8);
            *(bf16x8*)((char*)xlds + swz) = val;
        }
        for (int pt = t; pt < (int)m; pt += 256) combs[pt] = comb[pc + pt];
        __syncthreads();

        // MFMA: 16 points x 64 channels per wave (idle waves skip)
        if ((unsigned)(w * 16) < m) {
            int row = w * 16 + (l & 15);
            unsigned base = (unsigned)(row * 128 + ((l >> 4) << 4));
            unsigned sw = (unsigned)(row & 7) << 4;
            bf16x8 a0 = *(const bf16x8*)((char*)xlds + ((base + 0) ^ sw));
            bf16x8 a1 = *(const bf16x8*)((char*)xlds + ((base + 64) ^ sw));
            #pragma unroll
            for (int n = 0; n < 4; ++n) {
                f32x4 acc = {0.f, 0.f, 0.f, 0.f};
                acc = __builtin_amdgcn_mfma_f32_16x16x32_bf16(a0, bfr[n][0], acc, 0, 0, 0);
                acc = __builtin_amdgcn_mfma_f32_16x16x32_bf16(a1, bfr[n][1], acc, 0, 0, 0);
                int ch = n * 16 + (l & 15);
                #pragma unroll
                for (int r = 0; r < 4; ++r) {
                    int pidx = w * 16 + (l >> 4) * 4 + r;   // C: row=(l>>4)*4+r
                    if (pidx < (int)m) {
                        unsigned u = combs[pidx];
                        float v = fmaxf(acc[r] + bia[n], 0.0f);
                        ptfeat[(size_t)(u & 0x3FFFFu) * 64 + ch] = v;
                        atomicMax(&voxl[u >> 18][ch], __float_as_uint(v));
                    }
                }
            }
        }
        __syncthreads();
    }

    // transposed canvas write
    {
        float* cv = canvas + (size_t)batch * 64 * NSEG + vid0;
        #pragma unroll
        for (int i = 0; i < 16; ++i) {
            int c = i * 4 + w;
            cv[(size_t)c * NSEG + l] = __uint_as_float(voxl[l][c]);
        }
    }
}

// ---------------------------------------------------------------------------
extern "C" void kernel_launch(void* const* d_in, const int* in_sizes, int n_in,
                              void* d_out, int out_size, void* d_ws, size_t ws_size,
                              hipStream_t stream) {
    const float* pts = (const float*)d_in[0];
    const float* w0  = (const float*)d_in[1];
    const float* g0  = (const float*)d_in[2];
    const float* b0  = (const float*)d_in[3];
    const float* m0  = (const float*)d_in[4];
    const float* v0  = (const float*)d_in[5];
    const float* w1  = (const float*)d_in[6];
    const float* g1  = (const float*)d_in[7];
    const float* b1  = (const float*)d_in[8];
    const float* m1  = (const float*)d_in[9];
    const float* v1  = (const float*)d_in[10];
    float* out = (float*)d_out;
    float* ptfeat = out + (size_t)NB * 64 * NSEG;   // point_feats after canvases

    // workspace layout (~41 MB)
    char* ws = (char*)d_ws;
    size_t off = 0;
    unsigned int* cnt   = (unsigned int*)(ws + off); off += (size_t)NSEGT * 4;
    unsigned int* offs  = (unsigned int*)(ws + off); off += (size_t)NSEGT * 4;
    unsigned int* rank  = (unsigned int*)(ws + off); off += (size_t)NPTS * 4;
    unsigned int* comb  = (unsigned int*)(ws + off); off += (size_t)NPTS * 4;
    float4* sxyz        = (float4*)(ws + off);       off += (size_t)NPTS * 16;
    unsigned short* xbf = (unsigned short*)(ws + off); off += (size_t)NPTS * 64 * 2;
    unsigned short* wtbf= (unsigned short*)(ws + off); off += 4096 * 2;
    float* bias1f       = (float*)(ws + off);        off += 64 * 4;
    unsigned int* bsum  = (unsigned int*)(ws + off); off += 512 * 4;
    unsigned int* tick  = (unsigned int*)(ws + off); off += 4;

    int nblk = (NPTS + 255) / 256;
    k_init<<<513, 256, 0, stream>>>(cnt, w1, g1, b1, m1, v1, wtbf, bias1f, tick);
    k_stats<<<nblk, 256, 0, stream>>>(pts, cnt, rank);
    k_scan1<<<NSEGT / 1024, 256, 0, stream>>>(cnt, offs, bsum, tick);
    k_reorder<<<nblk, 256, 0, stream>>>(pts, rank, offs, bsum, sxyz, comb);
    k_pfn0<<<nblk, 256, 0, stream>>>(sxyz, offs, bsum, cnt,
                                     w0, g0, b0, m0, v0, xbf);
    k_pfn1<<<NB * 4096, 256, 0, stream>>>(xbf, comb, offs, bsum, cnt,
                                          wtbf, bias1f, ptfeat, out);
}

// Round 10
// 129.094 us; speedup vs baseline: 1.5524x; 1.4021x over previous
//
#include <hip/hip_runtime.h>

#define NPT   120000            // points per batch
#define NB    2                 // batches
#define NSEG  262144            // 512*512 pillars
#define NXg   512
#define NSEGT (NB * NSEG)       // 524288 total segments
#define NPTS  (NB * NPT)        // 240000 total points

typedef __attribute__((ext_vector_type(8))) short  bf16x8;
typedef __attribute__((ext_vector_type(4))) float  f32x4;

__device__ __forceinline__ unsigned short f2bf(float f) {
    unsigned u = __float_as_uint(f);
    return (unsigned short)((u + 0x7FFFu + ((u >> 16) & 1u)) >> 16);   // RNE
}

// ---------------------------------------------------------------------------
// K0: zero cnt (custom fill — rocclr fill ran at 18 GB/s for 2 MB)
//     + BN-fold layer-1 weights (transposed bf16) in the extra block.
// ---------------------------------------------------------------------------
__global__ __launch_bounds__(256) void k_init(unsigned int* __restrict__ cnt,
                                              const float* __restrict__ w1,
                                              const float* __restrict__ g1,
                                              const float* __restrict__ b1,
                                              const float* __restrict__ m1,
                                              const float* __restrict__ v1,
                                              unsigned short* __restrict__ wtbf,
                                              float* __restrict__ bias1f) {
    int t = threadIdx.x;
    if (blockIdx.x < 512) {
        int idx = blockIdx.x * 256 + t;          // 131072 uint4 = 2 MB
        ((uint4*)cnt)[idx] = make_uint4(0u, 0u, 0u, 0u);
        return;
    }
    // prep block
    #pragma unroll
    for (int i = 0; i < 16; ++i) {
        int idx = t + i * 256;                   // idx = c*64 + k
        int c = idx >> 6, k = idx & 63;
        float al = g1[c] * rsqrtf(v1[c] + 1e-3f);
        wtbf[idx] = f2bf(w1[k * 64 + c] * al);
    }
    if (t < 64) bias1f[t] = b1[t] - m1[t] * (g1[t] * rsqrtf(v1[t] + 1e-3f));
}

// ---------------------------------------------------------------------------
// K1: pillar id -> count atomic + arrival rank
// ---------------------------------------------------------------------------
__global__ __launch_bounds__(256) void k_stats(const float* __restrict__ pts,
                                               unsigned int* __restrict__ cnt,
                                               unsigned int* __restrict__ rank) {
    int tid = blockIdx.x * 256 + threadIdx.x;
    if (tid >= NPTS) return;
    const float* p = pts + (size_t)tid * 3;
    float x = p[0], y = p[1];
    // EXACT reference arithmetic: floor((x - lo)/vs), IEEE fp32 divide
    int xi = (int)floorf((x - (-51.2f)) / 0.2f);
    int yi = (int)floorf((y - (-51.2f)) / 0.2f);
    xi = min(max(xi, 0), 511);
    yi = min(max(yi, 0), 511);
    int b = (tid >= NPT) ? 1 : 0;
    int gvid = b * NSEG + (yi * NXg + xi);
    rank[tid] = atomicAdd(&cnt[gvid], 1u);
}

// ---------------------------------------------------------------------------
// Prefix scan of cnt[524288]: block-local offs + bsum, then scan bsum.
// Consumers add bsum[g>>10].  (Separate scan2: the tick-fused variant with
// per-block device-scope threadfence regressed ~50 µs in R8/R9.)
// ---------------------------------------------------------------------------
__global__ __launch_bounds__(256) void k_scan1(const unsigned int* __restrict__ cnt,
                                               unsigned int* __restrict__ offs,
                                               unsigned int* __restrict__ bsum) {
    __shared__ unsigned int s[256];
    int t = threadIdx.x;
    size_t base = (size_t)blockIdx.x * 1024 + t * 4;
    uint4 c4 = *(const uint4*)(cnt + base);
    unsigned int tsum = c4.x + c4.y + c4.z + c4.w;
    s[t] = tsum;
    __syncthreads();
    for (int o = 1; o < 256; o <<= 1) {
        unsigned int v = (t >= o) ? s[t - o] : 0u;
        __syncthreads();
        s[t] += v;
        __syncthreads();
    }
    unsigned int pre = s[t] - tsum;          // exclusive within block
    if (t == 255) bsum[blockIdx.x] = s[255];
    uint4 o4;
    o4.x = pre; o4.y = pre + c4.x; o4.z = o4.y + c4.y; o4.w = o4.z + c4.z;
    *(uint4*)(offs + base) = o4;
}

__global__ __launch_bounds__(256) void k_scan2(unsigned int* __restrict__ bsum) {
    __shared__ unsigned int s[256];
    int t = threadIdx.x;
    unsigned int a = bsum[2 * t], b = bsum[2 * t + 1];
    unsigned int ts = a + b;
    s[t] = ts;
    __syncthreads();
    for (int o = 1; o < 256; o <<= 1) {
        unsigned int v = (t >= o) ? s[t - o] : 0u;
        __syncthreads();
        s[t] += v;
        __syncthreads();
    }
    unsigned int pre = s[t] - ts;
    bsum[2 * t] = pre;
    bsum[2 * t + 1] = pre + a;
}

// ---------------------------------------------------------------------------
// K2: counting-sort apply. pos = offs[gvid] + bsum[g>>10] + rank.
//     comb packs (vid&63)<<18 | tid  (tid < 2^18).
// ---------------------------------------------------------------------------
__global__ __launch_bounds__(256) void k_reorder(const float* __restrict__ pts,
                                                 const unsigned int* __restrict__ rank,
                                                 const unsigned int* __restrict__ offs,
                                                 const unsigned int* __restrict__ bsum,
                                                 float4* __restrict__ sxyz,
                                                 unsigned int* __restrict__ comb) {
    int tid = blockIdx.x * 256 + threadIdx.x;
    if (tid >= NPTS) return;
    const float* p = pts + (size_t)tid * 3;
    float x = p[0], y = p[1], z = p[2];
    int xi = (int)floorf((x - (-51.2f)) / 0.2f);
    int yi = (int)floorf((y - (-51.2f)) / 0.2f);
    xi = min(max(xi, 0), 511);
    yi = min(max(yi, 0), 511);
    int b = (tid >= NPT) ? 1 : 0;
    int gvid = b * NSEG + (yi * NXg + xi);
    unsigned pos = offs[gvid] + bsum[gvid >> 10] + rank[tid];
    sxyz[pos] = make_float4(x, y, z, __int_as_float(gvid));
    comb[pos] = ((unsigned)(gvid & 63) << 18) | (unsigned)tid;
}

// ---------------------------------------------------------------------------
// K3: PFN layer0, position-parallel. Computes pillar mean AND pillar pooled
//     max by recomputing sibling h0 (siblings contiguous, avg 1.46/point).
//     Writes the complete 128B bf16 X-row [h0 | pooled]  (8 uint4).
// ---------------------------------------------------------------------------
__global__ __launch_bounds__(256) void k_pfn0(const float4* __restrict__ sxyz,
                                              const unsigned int* __restrict__ offs,
                                              const unsigned int* __restrict__ bsum,
                                              const unsigned int* __restrict__ cnt,
                                              const float* __restrict__ w0,
                                              const float* __restrict__ g0,
                                              const float* __restrict__ b0,
                                              const float* __restrict__ m0,
                                              const float* __restrict__ v0,
                                              unsigned short* __restrict__ xbf) {
    __shared__ float w0f[256];   // BN-folded [8][32]
    __shared__ float bias0[32];
    int t = threadIdx.x;
    {
        int c = t & 31;
        float al = g0[c] * rsqrtf(v0[c] + 1e-3f);
        w0f[t] = w0[t] * al;
        if (t < 32) bias0[t] = b0[t] - m0[t] * al;
    }
    __syncthreads();

    int pos = blockIdx.x * 256 + t;
    if (pos >= NPTS) return;

    float4 me = sxyz[pos];
    int gvid = __float_as_int(me.w);
    int vid = gvid & (NSEG - 1);
    int xi = vid & (NXg - 1), yi = vid >> 9;

    unsigned off = offs[gvid] + bsum[gvid >> 10];
    unsigned n   = cnt[gvid];               // >= 1
    float sx = 0.f, sy = 0.f, sz = 0.f;
    for (unsigned i = 0; i < n; ++i) {
        float4 q = sxyz[off + i];
        sx += q.x; sy += q.y; sz += q.z;
    }
    float inv = 1.0f / (float)n;
    float mx = sx * inv, my = sy * inv, mz = sz * inv;
    float cx = ((float)xi + 0.5f) * 0.2f + (-51.2f);
    float cy = ((float)yi + 0.5f) * 0.2f + (-51.2f);

    float own[32], pool[32];
    #pragma unroll
    for (int c = 0; c < 32; ++c) { pool[c] = 0.0f; own[c] = 0.0f; }
    for (unsigned i = 0; i < n; ++i) {
        float4 q = sxyz[off + i];
        float f[8] = {q.x, q.y, q.z, q.x - mx, q.y - my, q.z - mz,
                      q.x - cx, q.y - cy};
        bool self = (off + i == (unsigned)pos);
        #pragma unroll
        for (int c = 0; c < 32; ++c) {
            float acc = bias0[c];
            #pragma unroll
            for (int k = 0; k < 8; ++k) acc += f[k] * w0f[k * 32 + c];
            acc = fmaxf(acc, 0.0f);
            pool[c] = fmaxf(pool[c], acc);
            if (self) own[c] = acc;
        }
    }

    // full 128B row: own -> dst[0..3], pool -> dst[4..7]
    unsigned wv[16];
    uint4* dst = (uint4*)(xbf + (size_t)pos * 64);
    #pragma unroll
    for (int c2 = 0; c2 < 16; ++c2)
        wv[c2] = (unsigned)f2bf(own[2 * c2]) | ((unsigned)f2bf(own[2 * c2 + 1]) << 16);
    dst[0] = make_uint4(wv[0],  wv[1],  wv[2],  wv[3]);
    dst[1] = make_uint4(wv[4],  wv[5],  wv[6],  wv[7]);
    dst[2] = make_uint4(wv[8],  wv[9],  wv[10], wv[11]);
    dst[3] = make_uint4(wv[12], wv[13], wv[14], wv[15]);
    #pragma unroll
    for (int c2 = 0; c2 < 16; ++c2)
        wv[c2] = (unsigned)f2bf(pool[2 * c2]) | ((unsigned)f2bf(pool[2 * c2 + 1]) << 16);
    dst[4] = make_uint4(wv[0],  wv[1],  wv[2],  wv[3]);
    dst[5] = make_uint4(wv[4],  wv[5],  wv[6],  wv[7]);
    dst[6] = make_uint4(wv[8],  wv[9],  wv[10], wv[11]);
    dst[7] = make_uint4(wv[12], wv[13], wv[14], wv[15]);
}

// ---------------------------------------------------------------------------
// K4 (fused MFMA): 64 pillars / 256-thread block (4 waves).
//   stage: linear coalesced copy of X rows (XOR-swizzled LDS), trimmed to
//          ceil16(m) rows; waves whose 16-row slice is empty skip MFMA.
//   B    : 16 points x 64 ch per wave via 8x mfma_f32_16x16x32_bf16
//   C    : transposed coalesced canvas write
// ---------------------------------------------------------------------------
__global__ __launch_bounds__(256) void k_pfn1(const unsigned short* __restrict__ xbf,
                                              const unsigned int* __restrict__ comb,
                                              const unsigned int* __restrict__ offs,
                                              const unsigned int* __restrict__ bsum,
                                              const unsigned int* __restrict__ cnt,
                                              const unsigned short* __restrict__ wtbf,
                                              const float* __restrict__ bias1f,
                                              float* __restrict__ ptfeat,
                                              float* __restrict__ canvas) {
    __shared__ unsigned short xlds[64 * 64]; // swizzled bf16 X rows (8KB)
    __shared__ unsigned voxl[64][65];        // fp32 bits, padded
    __shared__ unsigned combs[64];

    int t = threadIdx.x;
    int l = t & 63;                          // lane in wave
    int w = t >> 6;                          // wave 0..3

    int batch = blockIdx.x >> 12;            // 4096 blocks per batch
    int vid0 = (blockIdx.x & 4095) << 6;
    int gvid0 = batch * NSEG + vid0;

    #pragma unroll
    for (int i = 0; i < 17; ++i) {
        int idx = t + i * 256;
        if (idx < 64 * 65) ((unsigned*)voxl)[idx] = 0u;
    }

    unsigned poslo = offs[gvid0] + bsum[gvid0 >> 10];
    unsigned poshi;
    {
        int g2 = gvid0 + 63;
        poshi = offs[g2] + bsum[g2 >> 10] + cnt[g2];
    }

    // B-fragments: lane holds WT[c = n*16 + l%16][k = ks*32 + (l/16)*8 + e]
    bf16x8 bfr[4][2];
    float bia[4];
    #pragma unroll
    for (int n = 0; n < 4; ++n) {
        #pragma unroll
        for (int ks = 0; ks < 2; ++ks)
            bfr[n][ks] = *(const bf16x8*)(wtbf + ((n * 16 + (l & 15)) * 64 +
                                                  ks * 32 + (l >> 4) * 8));
        bia[n] = bias1f[n * 16 + (l & 15)];
    }
    __syncthreads();                         // voxl init visible (empty-tile path)

    for (unsigned pc = poslo; pc < poshi; pc += 64) {
        unsigned m = min(64u, poshi - pc);
        unsigned mc = (m + 15u) & ~15u;      // rows actually staged/consumed

        // stage: linear coalesced read of 128B rows, swizzled LDS write
        for (int idx = t; idx < (int)(mc * 8); idx += 256) {
            int pt = idx >> 3, seg = idx & 7;
            unsigned lin = (unsigned)(pt * 128 + seg * 16);
            unsigned swz = lin ^ ((unsigned)(pt & 7) << 4);
            bf16x8 val;
            #pragma unroll
            for (int e = 0; e < 8; ++e) val[e] = 0;
            if (pt < (int)m)
                val = *(const bf16x8*)(xbf + (size_t)(pc + pt) * 64 + seg * 8);
            *(bf16x8*)((char*)xlds + swz) = val;
        }
        for (int pt = t; pt < (int)m; pt += 256) combs[pt] = comb[pc + pt];
        __syncthreads();

        // MFMA: 16 points x 64 channels per wave (idle waves skip)
        if ((unsigned)(w * 16) < m) {
            int row = w * 16 + (l & 15);
            unsigned base = (unsigned)(row * 128 + ((l >> 4) << 4));
            unsigned sw = (unsigned)(row & 7) << 4;
            bf16x8 a0 = *(const bf16x8*)((char*)xlds + ((base + 0) ^ sw));
            bf16x8 a1 = *(const bf16x8*)((char*)xlds + ((base + 64) ^ sw));
            #pragma unroll
            for (int n = 0; n < 4; ++n) {
                f32x4 acc = {0.f, 0.f, 0.f, 0.f};
                acc = __builtin_amdgcn_mfma_f32_16x16x32_bf16(a0, bfr[n][0], acc, 0, 0, 0);
                acc = __builtin_amdgcn_mfma_f32_16x16x32_bf16(a1, bfr[n][1], acc, 0, 0, 0);
                int ch = n * 16 + (l & 15);
                #pragma unroll
                for (int r = 0; r < 4; ++r) {
                    int pidx = w * 16 + (l >> 4) * 4 + r;   // C: row=(l>>4)*4+r
                    if (pidx < (int)m) {
                        unsigned u = combs[pidx];
                        float v = fmaxf(acc[r] + bia[n], 0.0f);
                        ptfeat[(size_t)(u & 0x3FFFFu) * 64 + ch] = v;
                        atomicMax(&voxl[u >> 18][ch], __float_as_uint(v));
                    }
                }
            }
        }
        __syncthreads();
    }

    // transposed canvas write
    {
        float* cv = canvas + (size_t)batch * 64 * NSEG + vid0;
        #pragma unroll
        for (int i = 0; i < 16; ++i) {
            int c = i * 4 + w;
            cv[(size_t)c * NSEG + l] = __uint_as_float(voxl[l][c]);
        }
    }
}

// ---------------------------------------------------------------------------
extern "C" void kernel_launch(void* const* d_in, const int* in_sizes, int n_in,
                              void* d_out, int out_size, void* d_ws, size_t ws_size,
                              hipStream_t stream) {
    const float* pts = (const float*)d_in[0];
    const float* w0  = (const float*)d_in[1];
    const float* g0  = (const float*)d_in[2];
    const float* b0  = (const float*)d_in[3];
    const float* m0  = (const float*)d_in[4];
    const float* v0  = (const float*)d_in[5];
    const float* w1  = (const float*)d_in[6];
    const float* g1  = (const float*)d_in[7];
    const float* b1  = (const float*)d_in[8];
    const float* m1  = (const float*)d_in[9];
    const float* v1  = (const float*)d_in[10];
    float* out = (float*)d_out;
    float* ptfeat = out + (size_t)NB * 64 * NSEG;   // point_feats after canvases

    // workspace layout (~41 MB)
    char* ws = (char*)d_ws;
    size_t off = 0;
    unsigned int* cnt   = (unsigned int*)(ws + off); off += (size_t)NSEGT * 4;
    unsigned int* offs  = (unsigned int*)(ws + off); off += (size_t)NSEGT * 4;
    unsigned int* rank  = (unsigned int*)(ws + off); off += (size_t)NPTS * 4;
    unsigned int* comb  = (unsigned int*)(ws + off); off += (size_t)NPTS * 4;
    float4* sxyz        = (float4*)(ws + off);       off += (size_t)NPTS * 16;
    unsigned short* xbf = (unsigned short*)(ws + off); off += (size_t)NPTS * 64 * 2;
    unsigned short* wtbf= (unsigned short*)(ws + off); off += 4096 * 2;
    float* bias1f       = (float*)(ws + off);        off += 64 * 4;
    unsigned int* bsum  = (unsigned int*)(ws + off); off += 512 * 4;

    int nblk = (NPTS + 255) / 256;
    k_init<<<513, 256, 0, stream>>>(cnt, w1, g1, b1, m1, v1, wtbf, bias1f);
    k_stats<<<nblk, 256, 0, stream>>>(pts, cnt, rank);
    k_scan1<<<NSEGT / 1024, 256, 0, stream>>>(cnt, offs, bsum);
    k_scan2<<<1, 256, 0, stream>>>(bsum);
    k_reorder<<<nblk, 256, 0, stream>>>(pts, rank, offs, bsum, sxyz, comb);
    k_pfn0<<<nblk, 256, 0, stream>>>(sxyz, offs, bsum, cnt,
                                     w0, g0, b0, m0, v0, xbf);
    k_pfn1<<<NB * 4096, 256, 0, stream>>>(xbf, comb, offs, bsum, cnt,
                                          wtbf, bias1f, ptfeat, out);
}